// Round 9
// baseline (2257.449 us; speedup 1.0000x reference)
//
#include <hip/hip_runtime.h>

#define BB 64
#define TT 4096
#define HH 256
#define NTOK (BB * TT)

typedef _Float16 f16;
typedef _Float16 f16x8 __attribute__((ext_vector_type(8)));
typedef float f32x4 __attribute__((ext_vector_type(4)));
typedef unsigned int uint;
typedef unsigned short ushort;
typedef uint uint4v __attribute__((ext_vector_type(4)));

__device__ __forceinline__ uint packf16(float a, float b) {  // RNE pack (prep only)
    ushort lo = __builtin_bit_cast(ushort, (f16)a);
    ushort hi = __builtin_bit_cast(ushort, (f16)b);
    return (uint)lo | ((uint)hi << 16);
}

// ============ prep: W_hh -> MFMA A-fragment-major, per-RNN-thread contiguous ============
// RNN (256-thread) thread tid (lane=tid&63, w=tid>>6) holds frags fi = mt*8+ks
// (mt<4 m-tiles, ks<8 k-slices). Frag elem j:
// A[m=lane&15][k=32ks+8*(lane>>4)+j] = Whh[64w+16mt+(lane&15)][k].
__global__ __launch_bounds__(256) void rnn_wswz_kernel(const float* __restrict__ Whh,
                                                       uint4v* __restrict__ Wsw) {
    int gid = blockIdx.x * 256 + threadIdx.x;  // 8192 uint4 = 128 KiB
    if (gid >= 8192) return;
    int tid = gid >> 5, fi = gid & 31;
    int mt = fi >> 3, ks = fi & 7;
    int lane = tid & 63, w = tid >> 6;
    int hd = w * 64 + mt * 16 + (lane & 15);
    int kb = ks * 32 + ((lane >> 4) << 3);
    const float* p = Whh + hd * 256 + kb;
    uint4v v;
    v.x = packf16(p[0], p[1]);
    v.y = packf16(p[2], p[3]);
    v.z = packf16(p[4], p[5]);
    v.w = packf16(p[6], p[7]);
    Wsw[gid] = v;
}

// ============ prep: MLP weights -> MFMA B-fragment-major layout ============
__global__ __launch_bounds__(256) void bfrag_prep_kernel(const float* __restrict__ W,
                                                         uint4v* __restrict__ dst,
                                                         int N, int Kreal, int KS, int NT) {
    int gid = blockIdx.x * 256 + threadIdx.x;
    if (gid >= NT * KS * 64) return;
    int lane = gid & 63;
    int t = gid >> 6;
    int ks = t % KS, nt = t / KS;
    int n = nt * 16 + (lane & 15);
    int kb = ks * 32 + (lane >> 4) * 8;
    float f[8];
#pragma unroll
    for (int j = 0; j < 8; ++j) {
        int k = kb + j;
        f[j] = (n < N && k < Kreal) ? W[n * Kreal + k] : 0.f;
    }
    uint4v v;
    v.x = packf16(f[0], f[1]);
    v.y = packf16(f[2], f[3]);
    v.z = packf16(f[4], f[5]);
    v.w = packf16(f[6], f[7]);
    dst[gid] = v;
}

// ============ RNN: 64 blocks x 256 threads, inline-asm MFMA, W in true AGPRs ============
// 1 wave/SIMD. Wave w owns rows [64w,64w+64): A-frags wv[mt*8+ks] in 128 AGPRs,
// read DIRECTLY by v_mfma via "a" operand constraint (ISA: A may come from AGPR).
// VGPRs stay free (~90) so all 8 ds_reads pipeline. B = h broadcast from LDS.
// D lane (q=lane>>4, bl=lane&15): acc[mt][r] = pre[64w+16mt+4q+r] (all bl dup).
// Extract mt=bl>>2, r=bl&3 -> d = 64w+16(bl>>2)+4q+(bl&3): bijection over wave's 64.
// MFMA->VALU hazard fenced by acc-tied s_nop block (compiler can't see asm opcodes).
__global__ __launch_bounds__(256) __attribute__((amdgpu_waves_per_eu(1, 1))) void rnn_kernel(
        const float* __restrict__ x, const uint4v* __restrict__ Wsw,
        const float* __restrict__ Wih, const float* __restrict__ bih,
        const float* __restrict__ bhh, f16* __restrict__ ht, float* __restrict__ hlast) {
    const int b = blockIdx.x, tid = threadIdx.x;
    const int lane = tid & 63, w = tid >> 6;
    const int q = lane >> 4, bl = lane & 15;
    const int d = w * 64 + ((bl >> 2) << 4) + (q << 2) + (bl & 3);  // this lane's hdim
    __shared__ __align__(16) f16 hbuf[2][256];  // double-buffered h
    __shared__ uint4 xs[2][128];                // 64 timesteps x 32B, double-buffered

    uint4v wv[32];  // A-frags: wv[mt*8+ks] -> 128 AGPRs
    {
        const uint4v* wp = Wsw + (size_t)tid * 32;
#pragma unroll
        for (int i = 0; i < 32; ++i) wv[i] = wp[i];
    }
#pragma unroll
    for (int i = 0; i < 32; ++i) asm volatile("" : "+a"(wv[i]));  // pin to AGPR file

    float wih[7];
#pragma unroll
    for (int i = 0; i < 7; ++i) wih[i] = Wih[d * 7 + i];
    const float bias = bih[d] + bhh[d];

    const float* xb = x + (size_t)b * TT * 12;
    uint4 xpre = make_uint4(0, 0, 0, 0);
    if (tid < 128) {
        int row = tid >> 1, u = tid & 1;
        xs[0][row * 2 + u] = *(const uint4*)(xb + row * 12 + u * 4);
        xpre = *(const uint4*)(xb + (64 + row) * 12 + u * 4);
        ((uint*)hbuf[0])[tid] = 0;  // zero h0
    }
    __syncthreads();

    f16* htp = ht + (size_t)b * TT * 256 + d;  // PLAIN layout [b][t][j]
    ushort hst[16];

    for (int tb = 0; tb < 256; ++tb) {
#pragma unroll
        for (int k = 0; k < 16; ++k) {
            const int t = tb * 16 + k;
            const int cur = k & 1;
            const int tile = (t >> 6) & 1, tstep = t & 63;

            // B-frags FIRST (critical path): h[32ks+8q..+8), pure broadcast reads
            const uint4v* hq = (const uint4v*)hbuf[cur];
            uint4v hfr[8];
#pragma unroll
            for (int ks = 0; ks < 8; ++ks) hfr[ks] = hq[ks * 4 + q];

            // 4 independent acc chains (mt), round-robin over ks (dep spacing 4).
            // A read straight from AGPRs -- no accvgpr copies, no VGPR pressure.
            f32x4 acc[4];
#pragma unroll
            for (int mt = 0; mt < 4; ++mt) acc[mt] = (f32x4){0.f, 0.f, 0.f, 0.f};
#pragma unroll
            for (int ks = 0; ks < 8; ++ks) {
                f16x8 hb = __builtin_bit_cast(f16x8, hfr[ks]);
#pragma unroll
                for (int mt = 0; mt < 4; ++mt)
                    asm volatile("v_mfma_f32_16x16x32_f16 %0, %1, %2, %0"
                                 : "+v"(acc[mt])
                                 : "a"(wv[mt * 8 + ks]), "v"(hb));
            }
            // hazard fence: MFMA writes -> VALU reads of acc (24 nop cycles)
            asm volatile("s_nop 7\n\ts_nop 7\n\ts_nop 7"
                         : "+v"(acc[0]), "+v"(acc[1]), "+v"(acc[2]), "+v"(acc[3]));

            // x contribution (VALU co-issues with matrix pipe)
            const float4 xa = ((const float4*)xs[tile])[tstep * 2];
            const float4 xc = ((const float4*)xs[tile])[tstep * 2 + 1];
            float xw = fmaf(xa.x, wih[0], bias);
            xw = fmaf(xa.y, wih[1], xw);
            xw = fmaf(xa.z, wih[2], xw);
            xw = fmaf(xa.w, wih[3], xw);
            xw = fmaf(xc.x, wih[4], xw);
            xw = fmaf(xc.y, wih[5], xw);
            xw = fmaf(xc.z, wih[6], xw);

            // extract acc[bl>>2][bl&3]: 15 cndmask
            float t0[4];
#pragma unroll
            for (int mt = 0; mt < 4; ++mt) {
                float a01 = (bl & 1) ? acc[mt][1] : acc[mt][0];
                float a23 = (bl & 1) ? acc[mt][3] : acc[mt][2];
                t0[mt] = (bl & 2) ? a23 : a01;
            }
            float u0 = (bl & 4) ? t0[1] : t0[0];
            float u1 = (bl & 4) ? t0[3] : t0[2];
            float pre = ((bl & 8) ? u1 : u0) + xw;

            // tanh(x) = 2/(1+2^(c*x)) - 1, c = -2*log2(e)
            float e = __builtin_amdgcn_exp2f(-2.885390082f * pre);
            float rr = __builtin_amdgcn_rcpf(1.0f + e);
            float h = fmaf(2.0f, rr, -1.0f);

            f16 hf = (f16)h;
            hbuf[cur ^ 1][d] = hf;  // 64 distinct dims/wave, 2B, 2-way alias = free
            hst[k] = __builtin_bit_cast(ushort, hf);
            if (tb == 255 && k == 15) hlast[b * 256 + d] = h;

            if (tstep == 32 && tid < 128) {
                int row = tid >> 1, u = tid & 1;
                xs[tile ^ 1][row * 2 + u] = xpre;
                int nt = (t & ~63) + 128 + row;
                if (nt > TT - 1) nt = TT - 1;
                xpre = *(const uint4*)(xb + nt * 12 + u * 4);
            }
            asm volatile("s_waitcnt lgkmcnt(0)\n\ts_barrier" ::: "memory");
        }
        const size_t base = (size_t)(tb * 16) * 256;
#pragma unroll
        for (int k = 0; k < 16; ++k)
            htp[base + (size_t)k * 256] = __builtin_bit_cast(f16, hst[k]);
    }
}

// ============ MFMA MLP: 4096 blocks x 256 threads, 64 tokens/block ============
struct MlpB {
    const uint4v* bf[7];
    const float* bias[7];
};

template <int KS, int NT, bool MSPLIT>
__device__ __forceinline__ void mfma_layer(const uint4v* __restrict__ Bf,
                                           const float* __restrict__ bias, int Nreal,
                                           const uint4v* zin, uint4v* zout,
                                           int w, int lane, int m15, int q) {
    constexpr int NW = MSPLIT ? NT : (NT / 4);  // n-tiles per wave
    constexpr int MW = MSPLIT ? 1 : 4;          // m-tiles per wave
    const int ntb = MSPLIT ? 0 : w * NW;
    const int mtb = MSPLIT ? w : 0;
    f32x4 acc[MW][NW];
#pragma unroll
    for (int i = 0; i < MW; ++i)
#pragma unroll
        for (int j = 0; j < NW; ++j) acc[i][j] = (f32x4){0.f, 0.f, 0.f, 0.f};

#pragma unroll
    for (int ks = 0; ks < KS; ++ks) {
        f16x8 a[MW];
#pragma unroll
        for (int mt = 0; mt < MW; ++mt)
            a[mt] = __builtin_bit_cast(f16x8, zin[((mtb + mt) * 16 + m15) * 37 + ks * 4 + q]);
#pragma unroll
        for (int nt = 0; nt < NW; ++nt) {
            f16x8 b = __builtin_bit_cast(f16x8, Bf[((size_t)(ntb + nt) * KS + ks) * 64 + lane]);
#pragma unroll
            for (int mt = 0; mt < MW; ++mt)
                acc[mt][nt] =
                    __builtin_amdgcn_mfma_f32_16x16x32_f16(a[mt], b, acc[mt][nt], 0, 0, 0);
        }
    }
    f16* zo = (f16*)zout;
#pragma unroll
    for (int nt = 0; nt < NW; ++nt) {
        const int col = (ntb + nt) * 16 + m15;
        const float bv = (col < Nreal) ? bias[col] : 0.f;
#pragma unroll
        for (int mt = 0; mt < MW; ++mt) {
#pragma unroll
            for (int r = 0; r < 4; ++r) {
                float v = acc[mt][nt][r] + bv;
                v = fmaxf(v, 0.01f * v);  // leaky relu
                const int row = (mtb + mt) * 16 + q * 4 + r;
                zo[row * 296 + col] = (f16)v;
            }
        }
    }
}

__global__ __launch_bounds__(256) void mlp_kernel(const f16* __restrict__ ht,
                                                  const float* __restrict__ x,
                                                  MlpB P, float* __restrict__ out) {
    __shared__ uint4v z0[64 * 37];  // 37888 B each; ping-pong
    __shared__ uint4v z1[64 * 37];
    const int tid = threadIdx.x;
    const int w = tid >> 6, lane = tid & 63;
    const int m15 = lane & 15, q = lane >> 4;
    const int tok0 = blockIdx.x * 64;

    // stage z0 = [ht(256) | x_fixed(5) | 0-pad(27)] rows, 296-f16 stride
    for (int i = tid; i < 64 * 32; i += 256) {
        int r = i >> 5, u = i & 31;
        z0[r * 37 + u] = ((const uint4v*)(ht + (size_t)(tok0 + r) * 256))[u];
    }
    for (int i = tid; i < 64 * 5; i += 256) {
        int r = i / 5, u = 32 + (i % 5);
        uint4v v = {0u, 0u, 0u, 0u};
        if (u == 32) {
            const float* xp = x + (size_t)(tok0 + r) * 12 + 7;
            v.x = packf16(xp[0], xp[1]);
            v.y = packf16(xp[2], xp[3]);
            v.z = packf16(xp[4], 0.f);
        }
        z0[r * 37 + u] = v;
    }
    __syncthreads();

    mfma_layer<9, 16, false>(P.bf[0], P.bias[0], 256, z0, z1, w, lane, m15, q);
    __syncthreads();
    mfma_layer<8, 8, false>(P.bf[1], P.bias[1], 128, z1, z0, w, lane, m15, q);
    __syncthreads();
    mfma_layer<4, 4, false>(P.bf[2], P.bias[2], 64, z0, z1, w, lane, m15, q);
    __syncthreads();
    mfma_layer<2, 2, true>(P.bf[3], P.bias[3], 32, z1, z0, w, lane, m15, q);
    __syncthreads();
    mfma_layer<1, 1, true>(P.bf[4], P.bias[4], 16, z0, z1, w, lane, m15, q);
    __syncthreads();
    mfma_layer<1, 1, true>(P.bf[5], P.bias[5], 8, z1, z0, w, lane, m15, q);
    __syncthreads();

    // L6 head: K=8 (padded 32), N=7; no activation; fp32 out
    {
        f16x8 a = __builtin_bit_cast(f16x8, z0[(w * 16 + m15) * 37 + q]);
        f16x8 b = __builtin_bit_cast(f16x8, P.bf[6][lane]);
        f32x4 acc = (f32x4){0.f, 0.f, 0.f, 0.f};
        acc = __builtin_amdgcn_mfma_f32_16x16x32_f16(a, b, acc, 0, 0, 0);
        if (m15 < 7) {
            const float bv = P.bias[6][m15];
#pragma unroll
            for (int r = 0; r < 4; ++r)
                out[(size_t)(tok0 + w * 16 + q * 4 + r) * 7 + m15] = acc[r] + bv;
        }
    }
}

// ============ launch ============
extern "C" void kernel_launch(void* const* d_in, const int* in_sizes, int n_in,
                              void* d_out, int out_size, void* d_ws, size_t ws_size,
                              hipStream_t stream) {
    const float* x = (const float*)d_in[0];
    const float* Wih = (const float*)d_in[1];
    const float* Whh = (const float*)d_in[2];
    const float* bih = (const float*)d_in[3];
    const float* bhh = (const float*)d_in[4];
    const float* W[7];
    const float* bb[7];
    for (int j = 0; j < 7; ++j) {
        W[j] = (const float*)d_in[5 + 2 * j];
        bb[j] = (const float*)d_in[6 + 2 * j];
    }
    float* out = (float*)d_out;

    static const int Kd[7] = {261, 256, 128, 64, 32, 16, 8};
    static const int Nd[7] = {256, 128, 64, 32, 16, 8, 7};
    static const int KSd[7] = {9, 8, 4, 2, 1, 1, 1};
    static const int NTd[7] = {16, 8, 4, 2, 1, 1, 1};

    char* ws = (char*)d_ws;
    f16* ht = (f16*)ws;  // 128 MiB, plain [b][t][j]
    size_t off = (size_t)NTOK * HH * 2;
    uint4v* Wsw = (uint4v*)(ws + off);
    off += (size_t)8192 * 16;
    uint4v* bfp[7];
    for (int j = 0; j < 7; ++j) {
        bfp[j] = (uint4v*)(ws + off);
        off += (size_t)NTd[j] * KSd[j] * 64 * 16;
    }

    rnn_wswz_kernel<<<32, 256, 0, stream>>>(Whh, Wsw);
    for (int j = 0; j < 7; ++j) {
        int cnt = NTd[j] * KSd[j] * 64;
        bfrag_prep_kernel<<<(cnt + 255) / 256, 256, 0, stream>>>(W[j], bfp[j], Nd[j], Kd[j],
                                                                 KSd[j], NTd[j]);
    }

    rnn_kernel<<<BB, 256, 0, stream>>>(x, Wsw, Wih, bih, bhh, ht, out + (size_t)NTOK * 7);

    MlpB P;
    for (int j = 0; j < 7; ++j) {
        P.bf[j] = bfp[j];
        P.bias[j] = bb[j];
    }
    mlp_kernel<<<NTOK / 64, 256, 0, stream>>>(ht, x, P, out);
}

// Round 11
// 1890.870 us; speedup vs baseline: 1.1939x; 1.1939x over previous
//
#include <hip/hip_runtime.h>

#define BB 64
#define TT 4096
#define HH 256
#define NTOK (BB * TT)

typedef _Float16 f16;
typedef _Float16 f16x8 __attribute__((ext_vector_type(8)));
typedef float f32x4 __attribute__((ext_vector_type(4)));
typedef unsigned int uint;
typedef unsigned short ushort;
typedef uint uint4v __attribute__((ext_vector_type(4)));

__device__ __forceinline__ uint packf16(float a, float b) {  // RNE pack (prep only)
    ushort lo = __builtin_bit_cast(ushort, (f16)a);
    ushort hi = __builtin_bit_cast(ushort, (f16)b);
    return (uint)lo | ((uint)hi << 16);
}

// ============ prep: W_hh -> MFMA A-fragment-major, per-RNN-thread contiguous ============
// RNN (512-thread) thread tid (lane=tid&63, w=tid>>6) holds frags fi = mt*8+ks
// (mt<2 m-tiles, ks<8 k-slices). Frag elem j:
// A[m=lane&15][k=32ks+8*(lane>>4)+j] = Whh[32w+16mt+(lane&15)][k].
__global__ __launch_bounds__(256) void rnn_wswz_kernel(const float* __restrict__ Whh,
                                                       uint4v* __restrict__ Wsw) {
    int gid = blockIdx.x * 256 + threadIdx.x;  // 8192 uint4 = 128 KiB
    if (gid >= 8192) return;
    int tid = gid >> 4, fi = gid & 15;
    int mt = fi >> 3, ks = fi & 7;
    int lane = tid & 63, w = tid >> 6;
    int hd = w * 32 + mt * 16 + (lane & 15);
    int kb = ks * 32 + ((lane >> 4) << 3);
    const float* p = Whh + hd * 256 + kb;
    uint4v v;
    v.x = packf16(p[0], p[1]);
    v.y = packf16(p[2], p[3]);
    v.z = packf16(p[4], p[5]);
    v.w = packf16(p[6], p[7]);
    Wsw[gid] = v;
}

// ============ prep: xW[token][d] = sum_i x[t][i]*Wih[d][i] + bih[d] + bhh[d] (f32) ====
// Same fmaf order as the in-loop version -> bit-identical. One wave = one token;
// lane l computes dims 4l..4l+3; float4 stores coalesce to 1KB/wave.
__global__ __launch_bounds__(256) void xw_prep_kernel(const float* __restrict__ x,
                                                      const float* __restrict__ Wih,
                                                      const float* __restrict__ bih,
                                                      const float* __restrict__ bhh,
                                                      float* __restrict__ xwp) {
    int gid = blockIdx.x * 256 + threadIdx.x;
    int token = gid >> 6;
    if (token >= NTOK) return;
    int dq = (gid & 63) << 2;
    const float* xp = x + (size_t)token * 12;
    float xv[7];
#pragma unroll
    for (int i = 0; i < 7; ++i) xv[i] = xp[i];
    float4 o;
    float* op = &o.x;
#pragma unroll
    for (int j = 0; j < 4; ++j) {
        int dd = dq + j;
        float xw = fmaf(xv[0], Wih[dd * 7 + 0], bih[dd] + bhh[dd]);
#pragma unroll
        for (int i = 1; i < 7; ++i) xw = fmaf(xv[i], Wih[dd * 7 + i], xw);
        op[j] = xw;
    }
    *(float4*)(xwp + (size_t)token * 256 + dq) = o;
}

// ============ prep: MLP weights -> MFMA B-fragment-major layout ============
__global__ __launch_bounds__(256) void bfrag_prep_kernel(const float* __restrict__ W,
                                                         uint4v* __restrict__ dst,
                                                         int N, int Kreal, int KS, int NT) {
    int gid = blockIdx.x * 256 + threadIdx.x;
    if (gid >= NT * KS * 64) return;
    int lane = gid & 63;
    int t = gid >> 6;
    int ks = t % KS, nt = t / KS;
    int n = nt * 16 + (lane & 15);
    int kb = ks * 32 + (lane >> 4) * 8;
    float f[8];
#pragma unroll
    for (int j = 0; j < 8; ++j) {
        int k = kb + j;
        f[j] = (n < N && k < Kreal) ? W[n * Kreal + k] : 0.f;
    }
    uint4v v;
    v.x = packf16(f[0], f[1]);
    v.y = packf16(f[2], f[3]);
    v.z = packf16(f[4], f[5]);
    v.w = packf16(f[6], f[7]);
    dst[gid] = v;
}

// ============ RNN (main): 64 blocks x 512 threads, R4 structure + xW from global ======
// Wave w owns rows [32w,32w+32): A-frags wv[mt*8+ks] (mt<2) = 64 VGPRs pinned.
// B = h from LDS broadcast. Extract mt=bl>>3, r=bl&3 -> d = 32w+16(bl>>3)+4q+(bl&3).
// xw comes from precomputed xW via 1 global dword/step, prefetched 2 steps ahead
// (vmcnt NOT drained by the per-step lgkmcnt barrier -> loads span barriers).
__global__ __launch_bounds__(512) __attribute__((amdgpu_waves_per_eu(2, 2))) void rnn_kernel(
        const float* __restrict__ xwp, const uint4v* __restrict__ Wsw,
        f16* __restrict__ ht, float* __restrict__ hlast) {
    const int b = blockIdx.x, tid = threadIdx.x;
    const int lane = tid & 63, w = tid >> 6;
    const int q = lane >> 4, bl = lane & 15;
    const int d = w * 32 + ((bl >> 3) << 4) + (q << 2) + (bl & 3);  // this lane's hdim
    const bool writer = (bl & 4) == 0;
    __shared__ __align__(16) f16 hbuf[2][256];  // double-buffered h

    uint4v wv[16];  // A-frags: wv[mt*8+ks]
    {
        const uint4v* wp = Wsw + (size_t)tid * 16;
#pragma unroll
        for (int i = 0; i < 16; ++i) wv[i] = wp[i];
    }
#pragma unroll
    for (int i = 0; i < 16; ++i) asm volatile("" : "+v"(wv[i]));

    if (tid < 128) ((uint*)hbuf[0])[tid] = 0;  // zero h0
    __syncthreads();

    f16* htp = ht + (size_t)b * TT * 256 + d;        // PLAIN layout [b][t][j]
    const float* xg = xwp + (size_t)b * TT * 256 + d;
    float xwA = xg[0];
    float xwB = xg[256];
    ushort hst[16];

    for (int tb = 0; tb < 256; ++tb) {
#pragma unroll
        for (int k = 0; k < 16; ++k) {
            const int t = tb * 16 + k;
            const int cur = k & 1;

            // B-frags FIRST (critical path): h[32ks+8q..+8), pure broadcast reads
            const uint4v* hq = (const uint4v*)hbuf[cur];
            uint4v hfr[8];
#pragma unroll
            for (int ks = 0; ks < 8; ++ks) hfr[ks] = hq[ks * 4 + q];

            // 4 chains of depth 4, round-robin issue (dep spacing = 4 mfmas)
            f32x4 a0 = (f32x4){0.f, 0.f, 0.f, 0.f}, a1 = a0, a2 = a0, a3 = a0;
#pragma unroll
            for (int kk = 0; kk < 4; ++kk) {
                f16x8 hlo = __builtin_bit_cast(f16x8, hfr[kk]);
                f16x8 hhi = __builtin_bit_cast(f16x8, hfr[4 + kk]);
                a0 = __builtin_amdgcn_mfma_f32_16x16x32_f16(
                    __builtin_bit_cast(f16x8, wv[kk]), hlo, a0, 0, 0, 0);
                a1 = __builtin_amdgcn_mfma_f32_16x16x32_f16(
                    __builtin_bit_cast(f16x8, wv[4 + kk]), hhi, a1, 0, 0, 0);
                a2 = __builtin_amdgcn_mfma_f32_16x16x32_f16(
                    __builtin_bit_cast(f16x8, wv[8 + kk]), hlo, a2, 0, 0, 0);
                a3 = __builtin_amdgcn_mfma_f32_16x16x32_f16(
                    __builtin_bit_cast(f16x8, wv[12 + kk]), hhi, a3, 0, 0, 0);
            }

            // prefetch xw for t+2 (no deps -> issues early, flies across barriers)
            int tn = t + 2;
            if (tn > TT - 1) tn = TT - 1;
            float xwN = xg[(size_t)tn * 256];

            f32x4 acc0 = a0 + a1;  // m-tile 0
            f32x4 acc1 = a2 + a3;  // m-tile 1

            // extract acc[bl>>3][bl&3]: 7 cndmask
            float s0 = (bl & 8) ? acc1[0] : acc0[0];
            float s1 = (bl & 8) ? acc1[1] : acc0[1];
            float s2 = (bl & 8) ? acc1[2] : acc0[2];
            float s3 = (bl & 8) ? acc1[3] : acc0[3];
            float p01 = (bl & 1) ? s1 : s0;
            float p23 = (bl & 1) ? s3 : s2;
            float pre = ((bl & 2) ? p23 : p01) + xwA;

            // tanh(x) = 2/(1+2^(c*x)) - 1, c = -2*log2(e)
            float e = __builtin_amdgcn_exp2f(-2.885390082f * pre);
            float rr = __builtin_amdgcn_rcpf(1.0f + e);
            float h = fmaf(2.0f, rr, -1.0f);

            f16 hf = (f16)h;
            if (writer) hbuf[cur ^ 1][d] = hf;  // 32 writes/wave, 2B, conflict-free
            hst[k] = __builtin_bit_cast(ushort, hf);
            if (tb == 255 && k == 15 && writer) hlast[b * 256 + d] = h;

            xwA = xwB;
            xwB = xwN;
            asm volatile("s_waitcnt lgkmcnt(0)\n\ts_barrier" ::: "memory");
        }
        if (writer) {
            const size_t base = (size_t)(tb * 16) * 256;
#pragma unroll
            for (int k = 0; k < 16; ++k)
                htp[base + (size_t)k * 256] = __builtin_bit_cast(f16, hst[k]);
        }
    }
}

// ============ RNN (fallback, exact R4): used when ws too small for xW table ============
__global__ __launch_bounds__(512) __attribute__((amdgpu_waves_per_eu(2, 2))) void rnn_fb_kernel(
        const float* __restrict__ x, const uint4v* __restrict__ Wsw,
        const float* __restrict__ Wih, const float* __restrict__ bih,
        const float* __restrict__ bhh, f16* __restrict__ ht, float* __restrict__ hlast) {
    const int b = blockIdx.x, tid = threadIdx.x;
    const int lane = tid & 63, w = tid >> 6;
    const int q = lane >> 4, bl = lane & 15;
    const int d = w * 32 + ((bl >> 3) << 4) + (q << 2) + (bl & 3);
    const bool writer = (bl & 4) == 0;
    __shared__ __align__(16) f16 hbuf[2][256];
    __shared__ uint4 xs[2][128];

    uint4v wv[16];
    {
        const uint4v* wp = Wsw + (size_t)tid * 16;
#pragma unroll
        for (int i = 0; i < 16; ++i) wv[i] = wp[i];
    }
#pragma unroll
    for (int i = 0; i < 16; ++i) asm volatile("" : "+v"(wv[i]));

    float wih[7];
#pragma unroll
    for (int i = 0; i < 7; ++i) wih[i] = Wih[d * 7 + i];
    const float bias = bih[d] + bhh[d];

    const float* xb = x + (size_t)b * TT * 12;
    uint4 xpre = make_uint4(0, 0, 0, 0);
    if (tid < 128) {
        int row = tid >> 1, u = tid & 1;
        xs[0][row * 2 + u] = *(const uint4*)(xb + row * 12 + u * 4);
        xpre = *(const uint4*)(xb + (64 + row) * 12 + u * 4);
        ((uint*)hbuf[0])[tid] = 0;
    }
    __syncthreads();

    f16* htp = ht + (size_t)b * TT * 256 + d;
    ushort hst[16];

    for (int tb = 0; tb < 256; ++tb) {
#pragma unroll
        for (int k = 0; k < 16; ++k) {
            const int t = tb * 16 + k;
            const int cur = k & 1;
            const int tile = (t >> 6) & 1, tstep = t & 63;

            const uint4v* hq = (const uint4v*)hbuf[cur];
            uint4v hfr[8];
#pragma unroll
            for (int ks = 0; ks < 8; ++ks) hfr[ks] = hq[ks * 4 + q];

            f32x4 a0 = (f32x4){0.f, 0.f, 0.f, 0.f}, a1 = a0, a2 = a0, a3 = a0;
#pragma unroll
            for (int kk = 0; kk < 4; ++kk) {
                f16x8 hlo = __builtin_bit_cast(f16x8, hfr[kk]);
                f16x8 hhi = __builtin_bit_cast(f16x8, hfr[4 + kk]);
                a0 = __builtin_amdgcn_mfma_f32_16x16x32_f16(
                    __builtin_bit_cast(f16x8, wv[kk]), hlo, a0, 0, 0, 0);
                a1 = __builtin_amdgcn_mfma_f32_16x16x32_f16(
                    __builtin_bit_cast(f16x8, wv[4 + kk]), hhi, a1, 0, 0, 0);
                a2 = __builtin_amdgcn_mfma_f32_16x16x32_f16(
                    __builtin_bit_cast(f16x8, wv[8 + kk]), hlo, a2, 0, 0, 0);
                a3 = __builtin_amdgcn_mfma_f32_16x16x32_f16(
                    __builtin_bit_cast(f16x8, wv[12 + kk]), hhi, a3, 0, 0, 0);
            }

            const float4 xa = ((const float4*)xs[tile])[tstep * 2];
            const float4 xc = ((const float4*)xs[tile])[tstep * 2 + 1];
            float xw = fmaf(xa.x, wih[0], bias);
            xw = fmaf(xa.y, wih[1], xw);
            xw = fmaf(xa.z, wih[2], xw);
            xw = fmaf(xa.w, wih[3], xw);
            xw = fmaf(xc.x, wih[4], xw);
            xw = fmaf(xc.y, wih[5], xw);
            xw = fmaf(xc.z, wih[6], xw);

            f32x4 acc0 = a0 + a1;
            f32x4 acc1 = a2 + a3;

            float s0 = (bl & 8) ? acc1[0] : acc0[0];
            float s1 = (bl & 8) ? acc1[1] : acc0[1];
            float s2 = (bl & 8) ? acc1[2] : acc0[2];
            float s3 = (bl & 8) ? acc1[3] : acc0[3];
            float p01 = (bl & 1) ? s1 : s0;
            float p23 = (bl & 1) ? s3 : s2;
            float pre = ((bl & 2) ? p23 : p01) + xw;

            float e = __builtin_amdgcn_exp2f(-2.885390082f * pre);
            float rr = __builtin_amdgcn_rcpf(1.0f + e);
            float h = fmaf(2.0f, rr, -1.0f);

            f16 hf = (f16)h;
            if (writer) hbuf[cur ^ 1][d] = hf;
            hst[k] = __builtin_bit_cast(ushort, hf);
            if (tb == 255 && k == 15 && writer) hlast[b * 256 + d] = h;

            if (tstep == 32 && tid < 128) {
                int row = tid >> 1, u = tid & 1;
                xs[tile ^ 1][row * 2 + u] = xpre;
                int nt = (t & ~63) + 128 + row;
                if (nt > TT - 1) nt = TT - 1;
                xpre = *(const uint4*)(xb + nt * 12 + u * 4);
            }
            asm volatile("s_waitcnt lgkmcnt(0)\n\ts_barrier" ::: "memory");
        }
        if (writer) {
            const size_t base = (size_t)(tb * 16) * 256;
#pragma unroll
            for (int k = 0; k < 16; ++k)
                htp[base + (size_t)k * 256] = __builtin_bit_cast(f16, hst[k]);
        }
    }
}

// ============ MFMA MLP: 4096 blocks x 256 threads, 64 tokens/block ============
struct MlpB {
    const uint4v* bf[7];
    const float* bias[7];
};

template <int KS, int NT, bool MSPLIT>
__device__ __forceinline__ void mfma_layer(const uint4v* __restrict__ Bf,
                                           const float* __restrict__ bias, int Nreal,
                                           const uint4v* zin, uint4v* zout,
                                           int w, int lane, int m15, int q) {
    constexpr int NW = MSPLIT ? NT : (NT / 4);  // n-tiles per wave
    constexpr int MW = MSPLIT ? 1 : 4;          // m-tiles per wave
    const int ntb = MSPLIT ? 0 : w * NW;
    const int mtb = MSPLIT ? w : 0;
    f32x4 acc[MW][NW];
#pragma unroll
    for (int i = 0; i < MW; ++i)
#pragma unroll
        for (int j = 0; j < NW; ++j) acc[i][j] = (f32x4){0.f, 0.f, 0.f, 0.f};

#pragma unroll
    for (int ks = 0; ks < KS; ++ks) {
        f16x8 a[MW];
#pragma unroll
        for (int mt = 0; mt < MW; ++mt)
            a[mt] = __builtin_bit_cast(f16x8, zin[((mtb + mt) * 16 + m15) * 37 + ks * 4 + q]);
#pragma unroll
        for (int nt = 0; nt < NW; ++nt) {
            f16x8 b = __builtin_bit_cast(f16x8, Bf[((size_t)(ntb + nt) * KS + ks) * 64 + lane]);
#pragma unroll
            for (int mt = 0; mt < MW; ++mt)
                acc[mt][nt] =
                    __builtin_amdgcn_mfma_f32_16x16x32_f16(a[mt], b, acc[mt][nt], 0, 0, 0);
        }
    }
    f16* zo = (f16*)zout;
#pragma unroll
    for (int nt = 0; nt < NW; ++nt) {
        const int col = (ntb + nt) * 16 + m15;
        const float bv = (col < Nreal) ? bias[col] : 0.f;
#pragma unroll
        for (int mt = 0; mt < MW; ++mt) {
#pragma unroll
            for (int r = 0; r < 4; ++r) {
                float v = acc[mt][nt][r] + bv;
                v = fmaxf(v, 0.01f * v);  // leaky relu
                const int row = (mtb + mt) * 16 + q * 4 + r;
                zo[row * 296 + col] = (f16)v;
            }
        }
    }
}

__global__ __launch_bounds__(256) void mlp_kernel(const f16* __restrict__ ht,
                                                  const float* __restrict__ x,
                                                  MlpB P, float* __restrict__ out) {
    __shared__ uint4v z0[64 * 37];  // 37888 B each; ping-pong
    __shared__ uint4v z1[64 * 37];
    const int tid = threadIdx.x;
    const int w = tid >> 6, lane = tid & 63;
    const int m15 = lane & 15, q = lane >> 4;
    const int tok0 = blockIdx.x * 64;

    // stage z0 = [ht(256) | x_fixed(5) | 0-pad(27)] rows, 296-f16 stride
    for (int i = tid; i < 64 * 32; i += 256) {
        int r = i >> 5, u = i & 31;
        z0[r * 37 + u] = ((const uint4v*)(ht + (size_t)(tok0 + r) * 256))[u];
    }
    for (int i = tid; i < 64 * 5; i += 256) {
        int r = i / 5, u = 32 + (i % 5);
        uint4v v = {0u, 0u, 0u, 0u};
        if (u == 32) {
            const float* xp = x + (size_t)(tok0 + r) * 12 + 7;
            v.x = packf16(xp[0], xp[1]);
            v.y = packf16(xp[2], xp[3]);
            v.z = packf16(xp[4], 0.f);
        }
        z0[r * 37 + u] = v;
    }
    __syncthreads();

    mfma_layer<9, 16, false>(P.bf[0], P.bias[0], 256, z0, z1, w, lane, m15, q);
    __syncthreads();
    mfma_layer<8, 8, false>(P.bf[1], P.bias[1], 128, z1, z0, w, lane, m15, q);
    __syncthreads();
    mfma_layer<4, 4, false>(P.bf[2], P.bias[2], 64, z0, z1, w, lane, m15, q);
    __syncthreads();
    mfma_layer<2, 2, true>(P.bf[3], P.bias[3], 32, z1, z0, w, lane, m15, q);
    __syncthreads();
    mfma_layer<1, 1, true>(P.bf[4], P.bias[4], 16, z0, z1, w, lane, m15, q);
    __syncthreads();
    mfma_layer<1, 1, true>(P.bf[5], P.bias[5], 8, z1, z0, w, lane, m15, q);
    __syncthreads();

    // L6 head: K=8 (padded 32), N=7; no activation; fp32 out
    {
        f16x8 a = __builtin_bit_cast(f16x8, z0[(w * 16 + m15) * 37 + q]);
        f16x8 b = __builtin_bit_cast(f16x8, P.bf[6][lane]);
        f32x4 acc = (f32x4){0.f, 0.f, 0.f, 0.f};
        acc = __builtin_amdgcn_mfma_f32_16x16x32_f16(a, b, acc, 0, 0, 0);
        if (m15 < 7) {
            const float bv = P.bias[6][m15];
#pragma unroll
            for (int r = 0; r < 4; ++r)
                out[(size_t)(tok0 + w * 16 + q * 4 + r) * 7 + m15] = acc[r] + bv;
        }
    }
}

// ============ launch ============
extern "C" void kernel_launch(void* const* d_in, const int* in_sizes, int n_in,
                              void* d_out, int out_size, void* d_ws, size_t ws_size,
                              hipStream_t stream) {
    const float* x = (const float*)d_in[0];
    const float* Wih = (const float*)d_in[1];
    const float* Whh = (const float*)d_in[2];
    const float* bih = (const float*)d_in[3];
    const float* bhh = (const float*)d_in[4];
    const float* W[7];
    const float* bb[7];
    for (int j = 0; j < 7; ++j) {
        W[j] = (const float*)d_in[5 + 2 * j];
        bb[j] = (const float*)d_in[6 + 2 * j];
    }
    float* out = (float*)d_out;

    static const int Kd[7] = {261, 256, 128, 64, 32, 16, 8};
    static const int Nd[7] = {256, 128, 64, 32, 16, 8, 7};
    static const int KSd[7] = {9, 8, 4, 2, 1, 1, 1};
    static const int NTd[7] = {16, 8, 4, 2, 1, 1, 1};

    char* ws = (char*)d_ws;
    f16* ht = (f16*)ws;  // 128 MiB, plain [b][t][j]
    size_t off = (size_t)NTOK * HH * 2;
    uint4v* Wsw = (uint4v*)(ws + off);
    off += (size_t)8192 * 16;
    uint4v* bfp[7];
    for (int j = 0; j < 7; ++j) {
        bfp[j] = (uint4v*)(ws + off);
        off += (size_t)NTd[j] * KSd[j] * 64 * 16;
    }
    // xW table (f32): 256 MiB, only if workspace allows
    size_t xw_bytes = (size_t)NTOK * HH * 4;
    bool use_xw = (ws_size >= off + xw_bytes);
    float* xwp = (float*)(ws + off);

    rnn_wswz_kernel<<<32, 256, 0, stream>>>(Whh, Wsw);
    for (int j = 0; j < 7; ++j) {
        int cnt = NTd[j] * KSd[j] * 64;
        bfrag_prep_kernel<<<(cnt + 255) / 256, 256, 0, stream>>>(W[j], bfp[j], Nd[j], Kd[j],
                                                                 KSd[j], NTd[j]);
    }

    if (use_xw) {
        xw_prep_kernel<<<NTOK / 4, 256, 0, stream>>>(x, Wih, bih, bhh, xwp);
        rnn_kernel<<<BB, 512, 0, stream>>>(xwp, Wsw, ht, out + (size_t)NTOK * 7);
    } else {
        rnn_fb_kernel<<<BB, 512, 0, stream>>>(x, Wsw, Wih, bih, bhh, ht,
                                              out + (size_t)NTOK * 7);
    }

    MlpB P;
    for (int j = 0; j < 7; ++j) {
        P.bf[j] = bfp[j];
        P.bias[j] = bb[j];
    }
    mlp_kernel<<<NTOK / 64, 256, 0, stream>>>(ht, x, P, out);
}